// Round 4
// baseline (315.931 us; speedup 1.0000x reference)
//
#include <hip/hip_runtime.h>

// ComplexSuperposition: B=128, T=128, D=512 — FUSED single kernel.
//   or[b,d] = sum_t real[b,t,d]*w[b,t];  oi likewise
//   output_r[b,i,j] = or_i*or_j + oi_i*oi_j
//   output_i[b,i,j] = oi_i*or_j - or_i*oi_j
// Outputs flat: [output_r (B*D*D) | output_i (B*D*D)], f32.
//
// grid (2,128) = 256 blocks x 512 threads: block = (i-half, b).
// Phase 1: block reduces its b's full (T,D) slice (512 KB read, 2x redundant
//          across halves -> 134 MB total) into or/oi vectors in LDS.
// Phase 2: block writes its 256-row x 512-col outer-product half (1 MB).
// Floor: (134 MB read + 268 MB write) / 6.3 TB/s ~= 64 us.

#define B_  128
#define T_  128
#define D_  512
#define D4_ 128   // D/4

typedef float f32x4 __attribute__((ext_vector_type(4)));

__global__ __launch_bounds__(512)
void fused_kernel(const f32x4* __restrict__ xr,
                  const f32x4* __restrict__ xi,
                  const float* __restrict__ w,
                  f32x4* __restrict__ outR,
                  f32x4* __restrict__ outI)
{
    const int b    = blockIdx.y;
    const int half = blockIdx.x;          // 0..1 (i-range half)
    const int tid  = threadIdx.x;         // 0..511
    const int c    = tid & (D4_ - 1);     // f4 column 0..127
    const int q    = tid >> 7;            // t-quarter 0..3 (32 t's each)

    // ---- Phase 1: weighted reduction over T ----
    __shared__ float ws[T_];
    if (tid < T_) ws[tid] = w[b * T_ + tid];
    __syncthreads();

    float wreg[32];
    #pragma unroll
    for (int k = 0; k < 32; ++k) wreg[k] = ws[q * 32 + k];

    const f32x4* br = xr + ((size_t)b * T_ + q * 32) * D4_ + c;
    const f32x4* bm = xi + ((size_t)b * T_ + q * 32) * D4_ + c;

    f32x4 ar = (f32x4)0.f;
    f32x4 ai = (f32x4)0.f;
    #pragma unroll
    for (int k = 0; k < 32; ++k) {
        ar += br[k * D4_] * wreg[k];
        ai += bm[k * D4_] * wreg[k];
    }

    __shared__ __align__(16) f32x4 pr[4][D4_];   // 8 KB
    __shared__ __align__(16) f32x4 pi[4][D4_];   // 8 KB
    pr[q][c] = ar;
    pi[q][c] = ai;
    __syncthreads();

    __shared__ __align__(16) f32x4 sor4[D4_];    // 2 KB
    __shared__ __align__(16) f32x4 soi4[D4_];    // 2 KB
    if (q == 0) {
        #pragma unroll
        for (int k = 1; k < 4; ++k) { ar += pr[k][c]; ai += pi[k][c]; }
        sor4[c] = ar;
        soi4[c] = ai;
    }
    __syncthreads();

    // ---- Phase 2: outer products for i in [half*256, half*256+256) ----
    const int j4   = tid & (D4_ - 1);
    const int isub = tid >> 7;            // 0..3; wave-uniform

    const f32x4 rj = sor4[j4];
    const f32x4 ij = soi4[j4];
    const float* sor = (const float*)sor4;
    const float* soi = (const float*)soi4;

    const int i0 = half * (D_ / 2);
    f32x4* __restrict__ pR = outR + ((size_t)b * D_ + i0) * D4_ + j4;
    f32x4* __restrict__ pI = outI + ((size_t)b * D_ + i0) * D4_ + j4;

    #pragma unroll 8
    for (int r = 0; r < D_ / 2 / 4; ++r) {        // 64 iterations
        const int   row = r * 4 + isub;           // 0..255 within half
        const float a = sor[i0 + row];            // LDS broadcast (uniform/wave)
        const float m = soi[i0 + row];

        const f32x4 oR = a * rj + m * ij;
        const f32x4 oI = m * rj - a * ij;

        pR[(size_t)row * D4_] = oR;
        pI[(size_t)row * D4_] = oI;
    }
}

extern "C" void kernel_launch(void* const* d_in, const int* in_sizes, int n_in,
                              void* d_out, int out_size, void* d_ws, size_t ws_size,
                              hipStream_t stream) {
    const float* xr = (const float*)d_in[0];   // (B, T, D) f32
    const float* xi = (const float*)d_in[1];   // (B, T, D) f32
    const float* w  = (const float*)d_in[2];   // (B, T)    f32

    float* out = (float*)d_out;                // [output_r | output_i]

    fused_kernel<<<dim3(2, B_), 512, 0, stream>>>(
        (const f32x4*)xr, (const f32x4*)xi, w,
        (f32x4*)out,
        (f32x4*)(out + (size_t)B_ * D_ * D_));
}